// Round 4
// baseline (105.416 us; speedup 1.0000x reference)
//
#include <hip/hip_runtime.h>

#define NC 1024
#define DY 16
#define NG 65536

typedef float v4f __attribute__((ext_vector_type(4)));
typedef _Float16 h8 __attribute__((ext_vector_type(8)));

// ---------------- Phase A: exp tables + YT + grid output ----------------
// WX[m,i,k] = exp2(-((gx_i - cx[m,k])*s0)^2), WY[m,j,k] likewise for y-dim.
// YT[m,ch,k] = f16(yc[m,k,ch]).  Also writes out_grid (tensor-product grid).
__global__ __launch_bounds__(256) void setconv_tables(
    const float* __restrict__ xc, const float* __restrict__ yc,
    const float* __restrict__ lsp,
    _Float16* __restrict__ WX, _Float16* __restrict__ WY,
    _Float16* __restrict__ YT,
    float* __restrict__ out_grid, int m)
{
    const int tid = blockIdx.x * 256 + threadIdx.x;
    const int T1 = m * 256 * NC;     // WX/WY threads
    const int T2 = m * DY * NC;      // YT threads

    if (tid < T1) {
        const float l0 = 1e-5f + log1pf(__expf(lsp[0]));
        const float l1 = 1e-5f + log1pf(__expf(lsp[1]));
        const float R  = 0.84932184f;          // sqrt(log2(e)/2)
        const float s0 = R / l0, s1 = R / l1;
        const int k  = tid & (NC - 1);
        const int i  = (tid >> 10) & 255;
        const int mm = tid >> 18;
        const float g = 1.0f + (float)(i - 128) * 0.015625f;
        const float2 cxy = ((const float2*)xc)[mm * NC + k];
        const float ux = (g - cxy.x) * s0;
        const float uy = (g - cxy.y) * s1;
        WX[tid] = (_Float16)__builtin_amdgcn_exp2f(-ux * ux);
        WY[tid] = (_Float16)__builtin_amdgcn_exp2f(-uy * uy);
    } else if (tid < T1 + T2) {
        const int t  = tid - T1;
        const int k  = t & (NC - 1);
        const int ch = (t >> 10) & 15;
        const int mm = t >> 14;
        YT[t] = (_Float16)yc[((size_t)(mm * NC + k)) * DY + ch];
    } else if (tid < T1 + T2 + m * NG) {
        const int t  = tid - (T1 + T2);
        const int g  = t & (NG - 1);
        const int mm = t >> 16;
        const float gx = 1.0f + (float)((g >> 8) - 128) * 0.015625f;
        const float gy = 1.0f + (float)((g & 255) - 128) * 0.015625f;
        ((float2*)out_grid)[(size_t)mm * NG + g] = make_float2(gx, gy);
    }
}

// ---------------- Phase B: Z = (WX ⊗ WY) · Y via f16 MFMA ----------------
// Block = (i, m): 4 waves × 4 M-tiles × 16 = full 256-j line.
// A-frag[m=r][k=q*8+jj] = wx[i,k] * wy[j0+t*16+r, k]  (4 v_pk_mul_f16)
// B-frag data = YT[ch=r][k-slice]; B-frag ones => density on the MFMA pipe.
__global__ __launch_bounds__(256) void setconv_main(
    const _Float16* __restrict__ WX, const _Float16* __restrict__ WY,
    const _Float16* __restrict__ YT,
    float* __restrict__ out_z)
{
    const int i    = blockIdx.x;
    const int mi   = blockIdx.y;
    const int tid  = threadIdx.x;
    const int wave = tid >> 6;
    const int lane = tid & 63;
    const int q    = lane >> 4;
    const int r    = lane & 15;
    const int j0   = wave * 64;

    const _Float16* wxp = WX + (((size_t)mi * 256 + i) << 10) + q * 8;
    const _Float16* wyp = WY + (((size_t)mi * 256 + j0 + r) << 10) + q * 8;
    const _Float16* ytp = YT + (((size_t)mi * DY + r) << 10) + q * 8;

    h8 ones;
#pragma unroll
    for (int e = 0; e < 8; ++e) ones[e] = (_Float16)1.0f;

    v4f accD[4], accS[4];
#pragma unroll
    for (int t = 0; t < 4; ++t) {
        accD[t] = (v4f){0.f, 0.f, 0.f, 0.f};
        accS[t] = (v4f){0.f, 0.f, 0.f, 0.f};
    }

#pragma unroll 4
    for (int ks = 0; ks < 32; ++ks) {
        const int ko = ks * 32;
        const h8 wx = *(const h8*)(wxp + ko);
        const h8 yt = *(const h8*)(ytp + ko);
#pragma unroll
        for (int t = 0; t < 4; ++t) {
            const h8 wy = *(const h8*)(wyp + (size_t)t * 16 * 1024 + ko);
            const h8 a  = wx * wy;   // 4x v_pk_mul_f16, MFMA-ready
            accD[t] = __builtin_amdgcn_mfma_f32_16x16x32_f16(a, yt,   accD[t], 0, 0, 0);
            accS[t] = __builtin_amdgcn_mfma_f32_16x16x32_f16(a, ones, accS[t], 0, 0, 0);
        }
    }

    // C/D: col(lane&15)=channel, row(q*4+reg)=j within tile (validated round 3)
    float* __restrict__ oz = out_z + ((size_t)mi * NG + (size_t)i * 256 + j0) * 17;
#pragma unroll
    for (int t = 0; t < 4; ++t) {
#pragma unroll
        for (int reg = 0; reg < 4; ++reg) {
            const int row = t * 16 + q * 4 + reg;
            oz[(size_t)row * 17 + r] = accD[t][reg];
            if (r == 0) oz[(size_t)row * 17 + 16] = accS[t][reg];  // all cols equal
        }
    }
}

extern "C" void kernel_launch(void* const* d_in, const int* in_sizes, int n_in,
                              void* d_out, int out_size, void* d_ws, size_t ws_size,
                              hipStream_t stream) {
    const float* xc  = (const float*)d_in[0];   // [m, 1024, 2]
    const float* yc  = (const float*)d_in[1];   // [m, 1024, 16]
    // d_in[2] = xt — unused by the reference output
    const float* lsp = (const float*)d_in[3];   // [2]

    const int m = in_sizes[0] / (NC * 2);       // = 2

    float* out_grid = (float*)d_out;                        // m*NG*2 floats
    float* out_z    = (float*)d_out + (size_t)m * NG * 2;   // m*NG*17 floats

    _Float16* WX = (_Float16*)d_ws;             // m*256*1024 f16
    _Float16* WY = WX + (size_t)m * 256 * NC;   // m*256*1024 f16
    _Float16* YT = WY + (size_t)m * 256 * NC;   // m*16*1024  f16

    const int total_a = m * 256 * NC + m * DY * NC + m * NG;
    dim3 gridA((total_a + 255) / 256);
    hipLaunchKernelGGL(setconv_tables, gridA, dim3(256), 0, stream,
                       xc, yc, lsp, WX, WY, YT, out_grid, m);

    dim3 gridB(256, m);
    hipLaunchKernelGGL(setconv_main, gridB, dim3(256), 0, stream,
                       WX, WY, YT, out_z);
}

// Round 5
// 74.535 us; speedup vs baseline: 1.4143x; 1.4143x over previous
//
#include <hip/hip_runtime.h>

#define NC 1024
#define DY 16
#define NG 65536

#define SZ_WXH (256 * 1024)   // h16 elems per m
#define SZ_WYA (256 * 1024)   // h16 elems per m (A-fragment order)
#define SZ_YTB (32 * 64 * 8)  // 16384 h16 elems per m (B-fragment order)

typedef float v4f __attribute__((ext_vector_type(4)));
typedef _Float16 h8 __attribute__((ext_vector_type(8)));

// ---------------- Phase A: fragment-ordered tables + grid output ----------------
__global__ __launch_bounds__(256) void setconv_tables(
    const float* __restrict__ xc, const float* __restrict__ yc,
    const float* __restrict__ lsp,
    _Float16* __restrict__ WXh, _Float16* __restrict__ WYA,
    _Float16* __restrict__ YTB, float* __restrict__ out_grid, int m)
{
    const int tid = blockIdx.x * 256 + threadIdx.x;
    const int T1 = m * SZ_WXH;
    const int T2 = T1 + m * SZ_WYA;
    const int T3 = T2 + m * SZ_YTB;
    const int T4 = T3 + m * NG;
    if (tid >= T4) return;

    if (tid < T2) {
        const float l0 = 1e-5f + log1pf(__expf(lsp[0]));
        const float l1 = 1e-5f + log1pf(__expf(lsp[1]));
        const float R  = 0.84932184f;   // sqrt(log2(e)/2)
        if (tid < T1) {
            // WXh[m][i][k], plain layout
            const int mm = tid >> 18;
            const int i  = (tid >> 10) & 255;
            const int k  = tid & 1023;
            const float g = 1.0f + (float)(i - 128) * 0.015625f;
            const float u = (g - xc[((size_t)mm * NC + k) * 2 + 0]) * (R / l0);
            WXh[tid] = (_Float16)__builtin_amdgcn_exp2f(-u * u);
        } else {
            // WYA[m][jt][ks][lane][jj]  (A-fragment order)
            const int t    = tid - T1;
            const int mm   = t >> 18;
            const int rem  = t & 262143;
            const int jj   = rem & 7;
            const int lane = (rem >> 3) & 63;
            const int ks   = (rem >> 9) & 31;
            const int jt   = rem >> 14;
            const int j = jt * 16 + (lane & 15);
            const int k = ks * 32 + ((lane >> 4) << 3) + jj;
            const float g = 1.0f + (float)(j - 128) * 0.015625f;
            const float u = (g - xc[((size_t)mm * NC + k) * 2 + 1]) * (R / l1);
            WYA[t] = (_Float16)__builtin_amdgcn_exp2f(-u * u);
        }
    } else if (tid < T3) {
        // YTB[m][ks][lane][jj]  (B-fragment order: ch = lane&15)
        const int t    = tid - T2;
        const int mm   = t >> 14;
        const int rem  = t & 16383;
        const int jj   = rem & 7;
        const int lane = (rem >> 3) & 63;
        const int ks   = rem >> 9;
        const int ch = lane & 15;
        const int k  = ks * 32 + ((lane >> 4) << 3) + jj;
        YTB[t] = (_Float16)yc[(((size_t)mm * NC + k) << 4) + ch];
    } else {
        const int t  = tid - T3;
        const int mm = t >> 16;
        const int g  = t & 65535;
        const float gx = 1.0f + (float)((g >> 8) - 128) * 0.015625f;
        const float gy = 1.0f + (float)((g & 255) - 128) * 0.015625f;
        ((float2*)out_grid)[(size_t)mm * NG + g] = make_float2(gx, gy);
    }
}

// ---------------- Phase B: Z = (WX ⊗ WY) · [Y | 1] via f16 MFMA ----------------
// Block: 2 i's × 4 jt (one jt per wave). A-frag = wy (coalesced global, pre-
// swizzled) * wx (LDS quad-broadcast). B data = yt (LDS, frag order); B ones =
// const regs -> density on the MFMA pipe. 4 blocks/CU, 16 waves/CU.
__global__ __launch_bounds__(256, 4) void setconv_main(
    const _Float16* __restrict__ WXh, const _Float16* __restrict__ WYA,
    const _Float16* __restrict__ YTB, float* __restrict__ out_z)
{
    __shared__ __align__(16) _Float16 yt_lds[SZ_YTB];   // 32 KB
    __shared__ __align__(16) _Float16 wx_lds[2][1024];  // 4 KB

    const int mi   = blockIdx.y;
    const int bx   = blockIdx.x;     // 0..511
    const int ig   = bx >> 2;        // 0..127 -> i0 = 2*ig
    const int jg   = bx & 3;
    const int tid  = threadIdx.x;
    const int wave = tid >> 6;
    const int lane = tid & 63;
    const int q    = lane >> 4;
    const int r    = lane & 15;
    const int jt   = jg * 4 + wave;
    const int i0   = ig * 2;

    // ---- stage YTB (32 KB) + 2 wx rows (4 KB), all linear float4 copies ----
    {
        const float4* src = (const float4*)(YTB + (size_t)mi * SZ_YTB);
        float4* dst = (float4*)yt_lds;
#pragma unroll
        for (int t = 0; t < 8; ++t) dst[tid + 256 * t] = src[tid + 256 * t];
        const float4* wsrc = (const float4*)(WXh + ((size_t)mi * 256 + i0) * 1024);
        ((float4*)wx_lds)[tid] = wsrc[tid];
    }
    __syncthreads();

    const _Float16* wyp = WYA + ((((size_t)mi * 16 + jt) * 32) * 64 + lane) * 8;

    h8 ones;
#pragma unroll
    for (int e = 0; e < 8; ++e) ones[e] = (_Float16)1.0f;

    v4f accD0 = {0.f,0.f,0.f,0.f}, accS0 = {0.f,0.f,0.f,0.f};
    v4f accD1 = {0.f,0.f,0.f,0.f}, accS1 = {0.f,0.f,0.f,0.f};

#pragma unroll 4
    for (int ks = 0; ks < 32; ++ks) {
        const h8 wy  = *(const h8*)(wyp + (size_t)ks * 512);          // coalesced dwordx4
        const h8 yt  = *(const h8*)(yt_lds + ((size_t)ks * 64 + lane) * 8);  // ds_read_b128
        const h8 wxa = *(const h8*)(&wx_lds[0][ks * 32 + q * 8]);     // quad-broadcast
        const h8 wxb = *(const h8*)(&wx_lds[1][ks * 32 + q * 8]);
        const h8 a0 = wy * wxa;   // 4x v_pk_mul_f16
        const h8 a1 = wy * wxb;
        accD0 = __builtin_amdgcn_mfma_f32_16x16x32_f16(a0, yt,   accD0, 0, 0, 0);
        accS0 = __builtin_amdgcn_mfma_f32_16x16x32_f16(a0, ones, accS0, 0, 0, 0);
        accD1 = __builtin_amdgcn_mfma_f32_16x16x32_f16(a1, yt,   accD1, 0, 0, 0);
        accS1 = __builtin_amdgcn_mfma_f32_16x16x32_f16(a1, ones, accS1, 0, 0, 0);
    }

    // C/D: col(lane&15)=channel, row(q*4+reg)=j within tile (validated r3/r4)
    float* __restrict__ oz0 = out_z + ((size_t)mi * NG + (size_t)i0 * 256 + jt * 16) * 17;
    float* __restrict__ oz1 = oz0 + 256 * 17;
#pragma unroll
    for (int reg = 0; reg < 4; ++reg) {
        const int row = q * 4 + reg;
        oz0[(size_t)row * 17 + r] = accD0[reg];
        oz1[(size_t)row * 17 + r] = accD1[reg];
        if (r == 0) {
            oz0[(size_t)row * 17 + 16] = accS0[reg];
            oz1[(size_t)row * 17 + 16] = accS1[reg];
        }
    }
}

extern "C" void kernel_launch(void* const* d_in, const int* in_sizes, int n_in,
                              void* d_out, int out_size, void* d_ws, size_t ws_size,
                              hipStream_t stream) {
    const float* xc  = (const float*)d_in[0];   // [m, 1024, 2]
    const float* yc  = (const float*)d_in[1];   // [m, 1024, 16]
    // d_in[2] = xt — unused by the reference output
    const float* lsp = (const float*)d_in[3];   // [2]

    const int m = in_sizes[0] / (NC * 2);       // = 2

    float* out_grid = (float*)d_out;                        // m*NG*2 floats
    float* out_z    = (float*)d_out + (size_t)m * NG * 2;   // m*NG*17 floats

    _Float16* WXh = (_Float16*)d_ws;
    _Float16* WYA = WXh + (size_t)m * SZ_WXH;
    _Float16* YTB = WYA + (size_t)m * SZ_WYA;

    const int total_a = m * (SZ_WXH + SZ_WYA + SZ_YTB + NG);
    dim3 gridA((total_a + 255) / 256);
    hipLaunchKernelGGL(setconv_tables, gridA, dim3(256), 0, stream,
                       xc, yc, lsp, WXh, WYA, YTB, out_grid, m);

    dim3 gridB(512, m);
    hipLaunchKernelGGL(setconv_main, gridB, dim3(256), 0, stream,
                       WXh, WYA, YTB, out_z);
}